// Round 6
// baseline (71.570 us; speedup 1.0000x reference)
//
#include <hip/hip_runtime.h>
#include <hip/hip_fp16.h>
#include <math.h>

#define TT 16
#define HH 64
#define WW 64
#define CC 128

// XOR row swizzle: logical row r -> physical row; keeps stride-8 / block-8
// LDS access patterns at <=2-way bank aliasing with zero padding.
#define LROW(r) (((r) & 0x38) | ((((r) >> 3) ^ (r)) & 7))

__device__ __forceinline__ float2 cadd(float2 a, float2 b){ return make_float2(a.x+b.x, a.y+b.y); }
__device__ __forceinline__ float2 csub(float2 a, float2 b){ return make_float2(a.x-b.x, a.y-b.y); }
__device__ __forceinline__ float2 cmul(float2 a, float2 b) {
    return make_float2(a.x*b.x - a.y*b.y, a.x*b.y + a.y*b.x);
}
__device__ __forceinline__ float2 cmac(float2 acc, float2 a, float2 b) {
    acc.x = fmaf(a.x, b.x, fmaf(-a.y, b.y, acc.x));
    acc.y = fmaf(a.x, b.y, fmaf(a.y, b.x, acc.y));
    return acc;
}
__device__ __forceinline__ float2 csq(float2 a) {
    return make_float2(a.x*a.x - a.y*a.y, 2.f*a.x*a.y);
}

// ---------------- radix butterflies ----------------
template<int SGN>
__device__ __forceinline__ void dft4(float2 b0, float2 b1, float2 b2, float2 b3,
                                     float2& y0, float2& y1, float2& y2, float2& y3) {
    float2 e0 = cadd(b0, b2), e1 = csub(b0, b2);
    float2 o0 = cadd(b1, b3), o1 = csub(b1, b3);
    y0 = cadd(e0, o0); y2 = csub(e0, o0);
    float2 r = make_float2((float)(-SGN) * o1.y, (float)SGN * o1.x);
    y1 = cadd(e1, r); y3 = csub(e1, r);
}

template<int SGN>
__device__ __forceinline__ void dft8(const float2* a, float2* X) {
    const float C = 0.70710678118654752f;
    float2 E0,E1,E2,E3,O0,O1,O2,O3;
    dft4<SGN>(a[0],a[2],a[4],a[6], E0,E1,E2,E3);
    dft4<SGN>(a[1],a[3],a[5],a[7], O0,O1,O2,O3);
    float2 T1 = make_float2(C*(O1.x - (float)SGN*O1.y), C*((float)SGN*O1.x + O1.y));
    float2 T2 = make_float2((float)(-SGN)*O2.y, (float)SGN*O2.x);
    float2 T3 = make_float2(-C*(O3.x + (float)SGN*O3.y), C*((float)SGN*O3.x - O3.y));
    X[0]=cadd(E0,O0); X[4]=csub(E0,O0);
    X[1]=cadd(E1,T1); X[5]=csub(E1,T1);
    X[2]=cadd(E2,T2); X[6]=csub(E2,T2);
    X[3]=cadd(E3,T3); X[7]=csub(E3,T3);
}

template<int SGN>
__device__ __forceinline__ void dft16(const float2* v, float2* X) {
    const float ct[10] = {1.f, 0.92387953251f, 0.70710678119f, 0.38268343236f, 0.f,
                          0.f, -0.70710678119f, 0.f, 0.f, -0.92387953251f};
    const float st[10] = {0.f, 0.38268343236f, 0.70710678119f, 0.92387953251f, 1.f,
                          0.f, 0.70710678119f, 0.f, 0.f, -0.38268343236f};
    float2 Z[16];
    #pragma unroll
    for (int h0 = 0; h0 < 4; ++h0) {
        float2 y0,y1,y2,y3;
        dft4<SGN>(v[h0], v[4+h0], v[8+h0], v[12+h0], y0,y1,y2,y3);
        float2 ys[4] = {y0,y1,y2,y3};
        #pragma unroll
        for (int k0 = 0; k0 < 4; ++k0) {
            int m = h0 * k0;
            float cc = ct[m], ss = (float)SGN * st[m];
            Z[k0*4 + h0] = make_float2(ys[k0].x*cc - ys[k0].y*ss,
                                       ys[k0].x*ss + ys[k0].y*cc);
        }
    }
    #pragma unroll
    for (int k0 = 0; k0 < 4; ++k0) {
        float2 y0,y1,y2,y3;
        dft4<SGN>(Z[k0*4+0], Z[k0*4+1], Z[k0*4+2], Z[k0*4+3], y0,y1,y2,y3);
        X[k0] = y0; X[k0+4] = y1; X[k0+8] = y2; X[k0+12] = y3;
    }
}

// ---------------- fused kernel prep: tanh + kw-DFT + kh-DFT, half2 out ----------------
__global__ __launch_bounds__(256) void k_prep(const float* __restrict__ Ak,
                                              const float* __restrict__ Bk,
                                              __half2* __restrict__ Ahw,
                                              __half2* __restrict__ Bhw) {
    __shared__ float Asl[7][7][64];
    __shared__ float Bsl[7][7][64];
    __shared__ float2 Awl[7][64];
    __shared__ float2 Bwl[7][64];
    __shared__ float2 tw64[64];
    int bid = blockIdx.x;
    int kt = bid / 66;
    int rem = bid % 66;
    int om = rem >> 1, chalf = rem & 1;
    int c0 = chalf * 64;
    int tid = threadIdx.x;
    for (int i = tid; i < 64; i += 256) {
        float s, cq; sincosf(-6.283185307179586f * i / 64.0f, &s, &cq);
        tw64[i] = make_float2(cq, s);
    }
    for (int i = tid; i < 49 * 64; i += 256) {
        int p = i >> 6, cl = i & 63;
        int kh = p / 7, kw = p % 7;
        int idx = (((c0 + cl) * 3 + kt) * 7 + kh) * 7 + kw;
        Asl[kh][kw][cl] = 0.9f * tanhf(Ak[idx]);
        Bsl[kh][kw][cl] = Bk[idx];
    }
    __syncthreads();
    for (int i = tid; i < 7 * 64; i += 256) {
        int kh = i >> 6, cl = i & 63;
        float2 aA = make_float2(0.f,0.f), aB = make_float2(0.f,0.f);
        #pragma unroll
        for (int kw = 0; kw < 7; ++kw) {
            float2 t = tw64[(om * (kw - 3)) & 63];
            float va = Asl[kh][kw][cl], vb = Bsl[kh][kw][cl];
            aA.x = fmaf(va, t.x, aA.x); aA.y = fmaf(va, t.y, aA.y);
            aB.x = fmaf(vb, t.x, aB.x); aB.y = fmaf(vb, t.y, aB.y);
        }
        Awl[kh][cl] = aA; Bwl[kh][cl] = aB;
    }
    __syncthreads();
    for (int i = tid; i < 64 * 64; i += 256) {
        int eta = i >> 6, cl = i & 63;
        float2 aA = make_float2(0.f,0.f), aB = make_float2(0.f,0.f);
        #pragma unroll
        for (int kh = 0; kh < 7; ++kh) {
            float2 t = tw64[(eta * (kh - 3)) & 63];
            aA = cmac(aA, Awl[kh][cl], t);
            aB = cmac(aB, Bwl[kh][cl], t);
        }
        int ep = ((eta & 7) << 3) | (eta >> 3);      // digit-swapped eta position
        int o = ((kt * 33 + om) * 64 + ep) * 128 + c0 + cl;
        Ahw[o] = __float22half2_rn(aA);
        Bhw[o] = __float22half2_rn(aB);
    }
}

// ------- pass 1: forward radix-8 FFT along W (real input), write omega<=32 as half2 -------
// Single 16KB LDS plane: fp32 input reals, overwritten in place by half2 stage-1 output.
__global__ __launch_bounds__(256) void p1(const float* __restrict__ x,
                                          __half2* __restrict__ bufh) {
    __shared__ float rf[64][64];          // 16 KB, aliased as half2 after stage 1
    __shared__ float2 tw64[64];
    __half2* zal = (__half2*)&rf[0][0];
    int bid = blockIdx.x;
    int chalf = bid & 1, h = (bid >> 1) & 63, t = bid >> 7;
    for (int i = threadIdx.x; i < 64; i += 256) {
        float s, cq; sincosf(-6.283185307179586f * i / 64.0f, &s, &cq);
        tw64[i] = make_float2(cq, s);
    }
    const float4* src4 = (const float4*)(x + (size_t)(t * HH + h) * WW * CC + chalf * 64);
    for (int i = threadIdx.x; i < 1024; i += 256) {
        int w = i >> 4, c4 = i & 15;
        float4 v = src4[w * 32 + c4];
        rf[w][c4*4+0] = v.x; rf[w][c4*4+1] = v.y;
        rf[w][c4*4+2] = v.z; rf[w][c4*4+3] = v.w;
    }
    __syncthreads();
    int c = threadIdx.x & 63, s4 = threadIdx.x >> 6;
    // stage 1 phase A: read all 16 inputs to registers
    float a2[2][8];
    #pragma unroll
    for (int g = 0; g < 2; ++g) {
        int h0 = s4 * 2 + g;
        #pragma unroll
        for (int h1 = 0; h1 < 8; ++h1) a2[g][h1] = rf[h1 * 8 + h0][c];
    }
    __syncthreads();   // all float reads complete before any half2 overwrite
    // stage 1 phase B: dft8 + twiddle, write half2 into the same plane
    #pragma unroll
    for (int g = 0; g < 2; ++g) {
        int h0 = s4 * 2 + g;
        float2 a[8], Y[8];
        #pragma unroll
        for (int h1 = 0; h1 < 8; ++h1) a[h1] = make_float2(a2[g][h1], 0.f);
        dft8<-1>(a, Y);
        #pragma unroll
        for (int k0 = 0; k0 < 8; ++k0) {
            float2 z = cmul(Y[k0], tw64[(h0 * k0) & 63]);
            zal[(k0 * 8 + h0) * 64 + c] = __float22half2_rn(z);
        }
    }
    __syncthreads();
    __half2* dst = bufh + (size_t)(t * HH + h) * WW * CC + chalf * 64 + c;
    #pragma unroll
    for (int g = 0; g < 2; ++g) {
        int k0 = s4 * 2 + g;
        float2 b[8], X[8];
        #pragma unroll
        for (int h0 = 0; h0 < 8; ++h0)
            b[h0] = __half22float2(zal[(k0 * 8 + h0) * 64 + c]);
        dft8<-1>(b, X);
        #pragma unroll
        for (int k1 = 0; k1 < 8; ++k1) {
            int om = k0 + 8 * k1;
            if (om <= 32) dst[(size_t)om * CC] = __float22half2_rn(X[k1]);
        }
    }
}

// ------- fused middle pass: H-FFT + T-FFT + G multiply + inv-T + inv-H, in place -------
// 256 threads, one block per (omega in [0..32], 4-channel chunk). 32KB LDS, 5 blocks/CU.
__global__ __launch_bounds__(256, 5) void pmid(__half2* __restrict__ bufh,
                                               const __half2* __restrict__ Ahw,
                                               const __half2* __restrict__ Bhw) {
    __shared__ float tre[16][64][4];      // 16 KB
    __shared__ float tim[16][64][4];      // 16 KB
    // XCD-chunked swizzle: 1056 = 8*132
    int l = (blockIdx.x & 7) * 132 + (blockIdx.x >> 3);
    int om = l >> 5, cc = l & 31;
    int c0 = cc * 4;
    int tid = threadIdx.x;

    // prefetch half2 G tables into registers (hidden under H stages)
    int cg = tid & 3, rT = tid >> 2;                 // T-phase mapping
    const int PKT = 33 * 64 * 128;
    int kb = (om * 64 + rT) * 128 + c0 + cg;
    __half2 a0h = Ahw[kb], a1h = Ahw[kb + PKT], a2h = Ahw[kb + 2*PKT];
    __half2 b0h = Bhw[kb], b1h = Bhw[kb + PKT], b2h = Bhw[kb + 2*PKT];

    int d = tid & 7;
    float twc[8], tws[8];
    {
        float s1, c1; sincosf(-6.283185307179586f * d / 64.0f, &s1, &c1);
        twc[0] = 1.f; tws[0] = 0.f;
        #pragma unroll
        for (int k = 1; k < 8; ++k) {
            twc[k] = twc[k-1]*c1 - tws[k-1]*s1;
            tws[k] = twc[k-1]*s1 + tws[k-1]*c1;
        }
    }
    // load tile: 16 B (4 complex half) per lane-iter
    for (int i = tid; i < 1024; i += 256) {
        int t = i >> 6, h = i & 63;
        const uint4* p4 = (const uint4*)(bufh + (((size_t)(t*64 + h)*64 + om)*128 + c0));
        uint4 u = *p4;
        float2 v0 = __half22float2(*(__half2*)&u.x);
        float2 v1 = __half22float2(*(__half2*)&u.y);
        float2 v2 = __half22float2(*(__half2*)&u.z);
        float2 v3 = __half22float2(*(__half2*)&u.w);
        int pr = LROW(h);
        tre[t][pr][0] = v0.x; tim[t][pr][0] = v0.y;
        tre[t][pr][1] = v1.x; tim[t][pr][1] = v1.y;
        tre[t][pr][2] = v2.x; tim[t][pr][2] = v2.y;
        tre[t][pr][3] = v3.x; tim[t][pr][3] = v3.y;
    }
    __syncthreads();
    int cl = (tid >> 3) & 3, ts = tid >> 5;          // ts in [0,8)
    // H forward stage 1: DFT8 over h1 at fixed h0=d, twiddle w^{-d*k0}
    #pragma unroll
    for (int q = 0; q < 2; ++q) {
        int t = ts*2 + q;
        float2 a[8], Y[8];
        #pragma unroll
        for (int h1 = 0; h1 < 8; ++h1) {
            int pr = LROW(h1*8 + d);
            a[h1] = make_float2(tre[t][pr][cl], tim[t][pr][cl]);
        }
        dft8<-1>(a, Y);
        #pragma unroll
        for (int k0 = 0; k0 < 8; ++k0) {
            int pr = LROW(k0*8 + d);
            tre[t][pr][cl] = Y[k0].x*twc[k0] - Y[k0].y*tws[k0];
            tim[t][pr][cl] = Y[k0].x*tws[k0] + Y[k0].y*twc[k0];
        }
    }
    __syncthreads();
    // H forward stage 2: DFT8 over h0 at fixed k0=d; row k0*8+k1 := bin k0+8*k1
    #pragma unroll
    for (int q = 0; q < 2; ++q) {
        int t = ts*2 + q;
        float2 a[8], Y[8];
        #pragma unroll
        for (int h0 = 0; h0 < 8; ++h0) {
            int pr = LROW(d*8 + h0);
            a[h0] = make_float2(tre[t][pr][cl], tim[t][pr][cl]);
        }
        dft8<-1>(a, Y);
        #pragma unroll
        for (int k1 = 0; k1 < 8; ++k1) {
            int pr = LROW(d*8 + k1);
            tre[t][pr][cl] = Y[k1].x; tim[t][pr][cl] = Y[k1].y;
        }
    }
    __syncthreads();
    // T phase: fwd dft16, G = S(A_f)*B_f multiply, inv dft16 (tables pre-permuted)
    {
        const float CT16[16] = {1.f, 0.9238795325f, 0.7071067812f, 0.3826834324f, 0.f,
                                -0.3826834324f, -0.7071067812f, -0.9238795325f, -1.f,
                                -0.9238795325f, -0.7071067812f, -0.3826834324f, 0.f,
                                0.3826834324f, 0.7071067812f, 0.9238795325f};
        const float ST16[16] = {0.f, 0.3826834324f, 0.7071067812f, 0.9238795325f, 1.f,
                                0.9238795325f, 0.7071067812f, 0.3826834324f, 0.f,
                                -0.3826834324f, -0.7071067812f, -0.9238795325f, -1.f,
                                -0.9238795325f, -0.7071067812f, -0.3826834324f};
        int pr = LROW(rT);
        float2 v[16], X[16];
        #pragma unroll
        for (int t = 0; t < 16; ++t) v[t] = make_float2(tre[t][pr][cg], tim[t][pr][cg]);
        dft16<-1>(v, X);
        float2 A0 = __half22float2(a0h), A1 = __half22float2(a1h), A2 = __half22float2(a2h);
        float2 B0 = __half22float2(b0h), B1 = __half22float2(b1h), B2 = __half22float2(b2h);
        #pragma unroll
        for (int ta = 0; ta < 16; ++ta) {
            float2 wv = make_float2(CT16[ta], -ST16[ta]);
            float2 wc = make_float2(CT16[ta],  ST16[ta]);
            float2 Af = A1; Af = cmac(Af, A0, wc); Af = cmac(Af, A2, wv);
            float2 Bf = B1; Bf = cmac(Bf, B0, wc); Bf = cmac(Bf, B2, wv);
            // S = sum_{k=0}^{7} Af^k = (1+Af)(1+Af^2)(1+Af^4)
            float2 A2q = csq(Af), A4q = csq(A2q);
            float2 S = cmul(make_float2(1.f+Af.x, Af.y), make_float2(1.f+A2q.x, A2q.y));
            S = cmul(S, make_float2(1.f+A4q.x, A4q.y));
            float2 G = cmul(S, Bf);
            X[ta] = cmul(X[ta], G);
        }
        dft16<1>(X, v);
        #pragma unroll
        for (int t = 0; t < 16; ++t) { tre[t][pr][cg] = v[t].x; tim[t][pr][cg] = v[t].y; }
    }
    __syncthreads();
    // inverse H stage 1: DFT8<+1> over eta1 at fixed eta0=d, twiddle w^{+d*h0}
    #pragma unroll
    for (int q = 0; q < 2; ++q) {
        int t = ts*2 + q;
        float2 a[8], Y[8];
        #pragma unroll
        for (int e1 = 0; e1 < 8; ++e1) {
            int pr = LROW(d*8 + e1);
            a[e1] = make_float2(tre[t][pr][cl], tim[t][pr][cl]);
        }
        dft8<1>(a, Y);
        #pragma unroll
        for (int h0 = 0; h0 < 8; ++h0) {
            int pr = LROW(d*8 + h0);
            tre[t][pr][cl] =  Y[h0].x*twc[h0] + Y[h0].y*tws[h0];
            tim[t][pr][cl] = -Y[h0].x*tws[h0] + Y[h0].y*twc[h0];
        }
    }
    __syncthreads();
    // inverse H stage 2: DFT8<+1> over eta0 at fixed h0=d; out row d+8*h1 (natural h)
    #pragma unroll
    for (int q = 0; q < 2; ++q) {
        int t = ts*2 + q;
        float2 a[8], Y[8];
        #pragma unroll
        for (int e0 = 0; e0 < 8; ++e0) {
            int pr = LROW(e0*8 + d);
            a[e0] = make_float2(tre[t][pr][cl], tim[t][pr][cl]);
        }
        dft8<1>(a, Y);
        #pragma unroll
        for (int h1 = 0; h1 < 8; ++h1) {
            int pr = LROW(d + 8*h1);
            tre[t][pr][cl] = Y[h1].x; tim[t][pr][cl] = Y[h1].y;
        }
    }
    __syncthreads();
    // write back with 1/64 fold, 16 B per lane-iter
    const float sc = 0.015625f;
    for (int i = tid; i < 1024; i += 256) {
        int t = i >> 6, h = i & 63;
        int pr = LROW(h);
        uint4 u;
        *(__half2*)&u.x = __float22half2_rn(make_float2(tre[t][pr][0]*sc, tim[t][pr][0]*sc));
        *(__half2*)&u.y = __float22half2_rn(make_float2(tre[t][pr][1]*sc, tim[t][pr][1]*sc));
        *(__half2*)&u.z = __float22half2_rn(make_float2(tre[t][pr][2]*sc, tim[t][pr][2]*sc));
        *(__half2*)&u.w = __float22half2_rn(make_float2(tre[t][pr][3]*sc, tim[t][pr][3]*sc));
        *(uint4*)(bufh + (((size_t)(t*64 + h)*64 + om)*128 + c0)) = u;
    }
}

// ------- pass 5: Hermitian-expand + inverse radix-8 FFT along W, real out, scale -------
// Single 16KB half2 plane, stage-1 rewrites it in place.
__global__ __launch_bounds__(256) void p5(const __half2* __restrict__ bufh,
                                          float* __restrict__ out) {
    __shared__ __half2 zal[64][64];       // 16 KB
    __shared__ float2 tw64[64];
    int bid = blockIdx.x;
    int chalf = bid & 1, h = (bid >> 1) & 63, t = bid >> 7;
    for (int i = threadIdx.x; i < 64; i += 256) {
        float s, cq; sincosf(6.283185307179586f * i / 64.0f, &s, &cq);
        tw64[i] = make_float2(cq, s);
    }
    const __half2* src = bufh + (size_t)(t * HH + h) * WW * CC + chalf * 64;
    for (int i = threadIdx.x; i < 33 * 64; i += 256) {
        int om = i >> 6, c = i & 63;
        __half2 v = src[(size_t)om * CC + c];
        zal[om][c] = v;
        if (om >= 1 && om <= 31) {        // Hermitian mirror (conjugate)
            __half2 m = v; m.y = __hneg(v.y);
            zal[64 - om][c] = m;
        }
    }
    __syncthreads();
    int c = threadIdx.x & 63, s4 = threadIdx.x >> 6;
    // stage 1 phase A: read all 16 inputs to registers
    float2 a2[2][8];
    #pragma unroll
    for (int g = 0; g < 2; ++g) {
        int h0 = s4 * 2 + g;
        #pragma unroll
        for (int h1 = 0; h1 < 8; ++h1) a2[g][h1] = __half22float2(zal[h1 * 8 + h0][c]);
    }
    __syncthreads();
    // stage 1 phase B: dft8 + twiddle, write back in place
    #pragma unroll
    for (int g = 0; g < 2; ++g) {
        int h0 = s4 * 2 + g;
        float2 Y[8];
        dft8<1>(a2[g], Y);
        #pragma unroll
        for (int k0 = 0; k0 < 8; ++k0) {
            float2 z = cmul(Y[k0], tw64[(h0 * k0) & 63]);
            zal[k0 * 8 + h0][c] = __float22half2_rn(z);
        }
    }
    __syncthreads();
    float* dst = out + (size_t)(t * HH + h) * WW * CC + chalf * 64 + c;
    #pragma unroll
    for (int g = 0; g < 2; ++g) {
        int k0 = s4 * 2 + g;
        float2 b[8], X[8];
        #pragma unroll
        for (int h0 = 0; h0 < 8; ++h0)
            b[h0] = __half22float2(zal[k0 * 8 + h0][c]);
        dft8<1>(b, X);
        #pragma unroll
        for (int k1 = 0; k1 < 8; ++k1)
            dst[(size_t)(k0 + 8 * k1) * CC] = X[k1].x * (1.0f / 1024.0f);
    }
}

extern "C" void kernel_launch(void* const* d_in, const int* in_sizes, int n_in,
                              void* d_out, int out_size, void* d_ws, size_t ws_size,
                              hipStream_t stream) {
    const float* x  = (const float*)d_in[0];
    const float* Ak = (const float*)d_in[1];
    const float* Bk = (const float*)d_in[2];
    float* out = (float*)d_out;

    __half2* bufh = (__half2*)d_ws;                          // 8.39M half2 (33.5MB)
    __half2* Ahw = bufh + (size_t)TT * HH * WW * CC;         // 3*33*64*128 half2 (1.6MB)
    __half2* Bhw = Ahw + 3 * 33 * 64 * 128;

    hipLaunchKernelGGL(k_prep, dim3(198),  dim3(256), 0, stream, Ak, Bk, Ahw, Bhw);
    hipLaunchKernelGGL(p1,     dim3(2048), dim3(256), 0, stream, x, bufh);
    hipLaunchKernelGGL(pmid,   dim3(1056), dim3(256), 0, stream, bufh, Ahw, Bhw);
    hipLaunchKernelGGL(p5,     dim3(2048), dim3(256), 0, stream, bufh, out);
}